// Round 8
// baseline (57.179 us; speedup 1.0000x reference)
//
#include <hip/hip_runtime.h>
#include <hip/hip_bf16.h>

// N=4, L=128, S=64, D=256, H=8. Heads collapse; weights pre-compose:
//   Mqk = Wq Wk^T, Mvo = Wv WoSum  (WoSum = sum_h Wo_h)
// Per slice sl=n*64+s: T = Xq@Mqk; S = T @ Xk^T (from staged LDS);
// P = softmax(S/16+mask); B1 = Xv@Mvo; out = P@B1 + bo.
// One block (512 thr / 8 waves, 128KB LDS) per slice.
// Frag convention: [tile][k8-chunk][lane(64)][j(8)]: lane l = row/col (l&15),
// k = k8*32+(l>>4)*8+j. A/B share the lane->k map (HW perm cancels);
// D layout row=4*(lane>>4)+j, col=lane&15.
// LDS: Areg [0,64K) staged X (swizzled rows, reused q->k->v)
//      Breg [64K,128K) T-image -> P(per-wave 4K) -> B1-image

using bf16x4 = __attribute__((ext_vector_type(4))) __bf16;
using bf16x8 = __attribute__((ext_vector_type(8))) __bf16;
using f32x4  = __attribute__((ext_vector_type(4))) float;

#define MFMA(a, b, c) __builtin_amdgcn_mfma_f32_16x16x32_bf16((a), (b), (c), 0, 0, 0)

__device__ __forceinline__ bf16x8 cvt8(float4 f0, float4 f1) {
  bf16x8 a;
  a[0]=(__bf16)f0.x; a[1]=(__bf16)f0.y; a[2]=(__bf16)f0.z; a[3]=(__bf16)f0.w;
  a[4]=(__bf16)f1.x; a[5]=(__bf16)f1.y; a[6]=(__bf16)f1.z; a[7]=(__bf16)f1.w;
  return a;
}

// ---------------------------------------------------------------- prep 1
// wosum[e2][eo] = sum_h Wo[(h*256+e2)*256+eo]   (fp32, coalesced both ways)
__global__ __launch_bounds__(256) void prep_wosum(
    const float* __restrict__ Wo, float* __restrict__ wosum) {
  int eo = threadIdx.x, e2 = blockIdx.x;
  float s = 0.f;
#pragma unroll
  for (int h = 0; h < 8; ++h) s += Wo[((size_t)(h * 256 + e2)) * 256 + eo];
  wosum[e2 * 256 + eo] = s;
}

// ---------------------------------------------------------------- prep 2
// mqk pack: Mqk[din][dout] = sum_e Wq[din][e] Wk[dout][e]
// mvo pack: Mvo[dv][eo]    = sum_e2 Wv[dv][e2] wosum[e2][eo]
// pack[ct][k8][lane][j]: slot=(lane&15)=dout/eo idx, k=k8*32+(lane>>4)*8+j=din/dv
__global__ __launch_bounds__(512) void prep_mm(
    const float* __restrict__ Wq, const float* __restrict__ Wk,
    const float* __restrict__ Wv, const float* __restrict__ wosum,
    __bf16* __restrict__ mqk, __bf16* __restrict__ mvo) {
  const int t = threadIdx.x, lane = t & 63, w = t >> 6;
  const int lr = lane & 15, g = lane >> 4;
  const bool isV = blockIdx.y != 0;
  const float* A = isV ? Wv : Wq;
  __bf16* dst = isV ? mvo : mqk;
  bf16x8 af0[8], af1[8];
#pragma unroll
  for (int k8 = 0; k8 < 8; ++k8) {
    const float* p0 = A + (size_t)((2 * w)     * 16 + lr) * 256 + k8 * 32 + g * 8;
    const float* p1 = A + (size_t)((2 * w + 1) * 16 + lr) * 256 + k8 * 32 + g * 8;
    af0[k8] = cvt8(*(const float4*)p0, *(const float4*)(p0 + 4));
    af1[k8] = cvt8(*(const float4*)p1, *(const float4*)(p1 + 4));
  }
#pragma unroll
  for (int c = 0; c < 2; ++c) {
    int ct = blockIdx.x * 2 + c;
    bf16x8 bf[8];
    if (!isV) {
#pragma unroll
      for (int k8 = 0; k8 < 8; ++k8) {
        const float* p = Wk + (size_t)(ct * 16 + lr) * 256 + k8 * 32 + g * 8;
        bf[k8] = cvt8(*(const float4*)p, *(const float4*)(p + 4));
      }
    } else {
#pragma unroll
      for (int k8 = 0; k8 < 8; ++k8)
#pragma unroll
        for (int jj = 0; jj < 8; ++jj)
          bf[k8][jj] = (__bf16)wosum[(size_t)(k8 * 32 + g * 8 + jj) * 256 + ct * 16 + lr];
    }
    f32x4 a0 = {0.f,0.f,0.f,0.f}, a1 = {0.f,0.f,0.f,0.f};
#pragma unroll
    for (int k8 = 0; k8 < 8; ++k8) {
      a0 = MFMA(af0[k8], bf[k8], a0);
      a1 = MFMA(af1[k8], bf[k8], a1);
    }
#pragma unroll
    for (int rtl = 0; rtl < 2; ++rtl) {
      const f32x4& ac = rtl ? a1 : a0;
      bf16x4 pb;
#pragma unroll
      for (int j = 0; j < 4; ++j) pb[j] = (__bf16)ac[j];
      size_t off = (size_t)ct * 4096 + w * 512 +
                   ((2 * rtl + (g >> 1)) * 16 + lr) * 8 + 4 * (g & 1);
      *reinterpret_cast<bf16x4*>(dst + off) = pb;
    }
  }
}

// ---------------------------------------------------------------- fused
__global__ __launch_bounds__(512, 2) void fused_attn(
    const float* __restrict__ Xv, const float* __restrict__ Xk,
    const float* __restrict__ Xq, const int* __restrict__ mask,
    const __bf16* __restrict__ mqk, const __bf16* __restrict__ mvo,
    const float* __restrict__ bo, float* __restrict__ out) {
  extern __shared__ char lds[];
  char* Areg = lds;                // 64KB staged X
  char* Breg = lds + 65536;        // 64KB images
  const int t = threadIdx.x, lane = t & 63, w = t >> 6;
  const int lr = lane & 15, g = lane >> 4;
  const int sl = blockIdx.x, n = sl >> 6, s = sl & 63;

  auto fill = [&](const float* __restrict__ X, float4* vr) {
#pragma unroll
    for (int i = 0; i < 8; ++i) {
      int f8 = i * 512 + t, row = f8 >> 5, c8 = f8 & 31;
      const float* src = X + ((size_t)(n * 8192 + row * 64 + s)) * 256 + c8 * 8;
      vr[2 * i]     = *reinterpret_cast<const float4*>(src);
      vr[2 * i + 1] = *reinterpret_cast<const float4*>(src + 4);
    }
  };
  auto flushv = [&](const float4* vr) {
#pragma unroll
    for (int i = 0; i < 8; ++i) {
      int f8 = i * 512 + t, row = f8 >> 5, c8 = f8 & 31;
      bf16x8 b;
      b[0]=(__bf16)vr[2*i].x;   b[1]=(__bf16)vr[2*i].y;
      b[2]=(__bf16)vr[2*i].z;   b[3]=(__bf16)vr[2*i].w;
      b[4]=(__bf16)vr[2*i+1].x; b[5]=(__bf16)vr[2*i+1].y;
      b[6]=(__bf16)vr[2*i+1].z; b[7]=(__bf16)vr[2*i+1].w;
      *reinterpret_cast<bf16x8*>(
          Areg + row * 512 + ((c8 * 16) ^ ((row & 7) << 4))) = b;
    }
  };

  // ---- phase 1: stage Xq
  {
    float4 vr[16];
    fill(Xq, vr);
    flushv(vr);
  }
  __syncthreads();                               // b1

  // ---- phase 2: T = Xq @ Mqk -> T-image in Breg (prefetch Xk)
  float4 vrp[16];
  fill(Xk, vrp);
  {
    const bf16x8* wp = reinterpret_cast<const bf16x8*>(mqk);
    bf16x8 wf0[8], wf1[8];
#pragma unroll
    for (int k8 = 0; k8 < 8; ++k8) {
      wf0[k8] = wp[((2 * w)     * 8 + k8) * 64 + lane];
      wf1[k8] = wp[((2 * w + 1) * 8 + k8) * 64 + lane];
    }
#pragma unroll
    for (int ct = 0; ct < 8; ++ct) {
      bf16x8 xf[8];
#pragma unroll
      for (int k8 = 0; k8 < 8; ++k8) {
        int brow = ct * 16 + lr;
        xf[k8] = *reinterpret_cast<const bf16x8*>(
            Areg + brow * 512 + ((k8 * 64 + g * 16) ^ ((brow & 7) << 4)));
      }
      f32x4 a0 = {0.f,0.f,0.f,0.f}, a1 = {0.f,0.f,0.f,0.f};
#pragma unroll
      for (int k8 = 0; k8 < 8; ++k8) {
        a0 = MFMA(wf0[k8], xf[k8], a0);
        a1 = MFMA(wf1[k8], xf[k8], a1);
      }
      bf16x4 p0, p1;
#pragma unroll
      for (int j = 0; j < 4; ++j) { p0[j] = (__bf16)a0[j]; p1[j] = (__bf16)a1[j]; }
      *reinterpret_cast<bf16x4*>(
          Breg + ct * 8192 + w * 1024 + (lr + 16 * (0 + (g >> 1))) * 16 + (g & 1) * 8) = p0;
      *reinterpret_cast<bf16x4*>(
          Breg + ct * 8192 + w * 1024 + (lr + 16 * (2 + (g >> 1))) * 16 + (g & 1) * 8) = p1;
    }
  }
  __syncthreads();                               // b2

  // ---- phase 3: hoist T A-frags, stage Xk
  bf16x8 af[8];
#pragma unroll
  for (int k8 = 0; k8 < 8; ++k8)
    af[k8] = *reinterpret_cast<const bf16x8*>(Breg + w * 8192 + k8 * 1024 + lane * 16);
  flushv(vrp);                                   // Xk -> Areg
  __syncthreads();                               // b3

  // ---- phase 4: S = T @ Xk^T directly from staged Xk (prefetch Xv + mask)
  fill(Xv, vrp);
  int mreg[8][4];
#pragma unroll
  for (int ct = 0; ct < 8; ++ct)
#pragma unroll
    for (int j = 0; j < 4; ++j)
      mreg[ct][j] = mask[((size_t)n * 128 + w * 16 + 4 * g + j) * 128 + ct * 16 + lr];
  f32x4 sacc[8];
#pragma unroll
  for (int ct = 0; ct < 8; ++ct) {
    bf16x8 xf[8];
#pragma unroll
    for (int k8 = 0; k8 < 8; ++k8) {
      int brow = ct * 16 + lr;
      xf[k8] = *reinterpret_cast<const bf16x8*>(
          Areg + brow * 512 + ((k8 * 64 + g * 16) ^ ((brow & 7) << 4)));
    }
    f32x4 a = {0.f,0.f,0.f,0.f};
#pragma unroll
    for (int k8 = 0; k8 < 8; ++k8) a = MFMA(af[k8], xf[k8], a);
    sacc[ct] = a;
  }
  __syncthreads();                               // b4 (Xk reads done)
  flushv(vrp);                                   // Xv -> Areg

  // ---- phase 5: softmax in regs (row q = w*16+4g+j spans ct x lr)
  float p[8][4];
#pragma unroll
  for (int j = 0; j < 4; ++j) {
    float mx = -3e38f;
#pragma unroll
    for (int ct = 0; ct < 8; ++ct) {
      float sv = mreg[ct][j] ? sacc[ct][j] * 0.0625f : -6.25e18f;  // -1e20/16
      p[ct][j] = sv;
      mx = fmaxf(mx, sv);
    }
#pragma unroll
    for (int o = 1; o < 16; o <<= 1) mx = fmaxf(mx, __shfl_xor(mx, o));
    float sum = 0.f;
#pragma unroll
    for (int ct = 0; ct < 8; ++ct) {
      float e = __expf(p[ct][j] - mx);
      p[ct][j] = e;
      sum += e;
    }
#pragma unroll
    for (int o = 1; o < 16; o <<= 1) sum += __shfl_xor(sum, o);
    float inv = 1.f / sum;
#pragma unroll
    for (int ct = 0; ct < 8; ++ct) p[ct][j] *= inv;
  }
  // P image (wave-local, Breg + w*4096), hoist pa
#pragma unroll
  for (int ct = 0; ct < 8; ++ct) {
    char* bse = Breg + w * 4096 + (ct >> 1) * 1024 +
                (16 * ((ct * 2 + (lr >> 3)) & 3)) * 16 + (lr & 7) * 2;
#pragma unroll
    for (int j = 0; j < 4; ++j)
      *reinterpret_cast<__bf16*>(bse + (4 * g + j) * 16) = (__bf16)p[ct][j];
  }
  bf16x8 pa[4];
#pragma unroll
  for (int kk8 = 0; kk8 < 4; ++kk8)
    pa[kk8] = *reinterpret_cast<const bf16x8*>(Breg + w * 4096 + kk8 * 1024 + lane * 16);
  __syncthreads();                               // b5 (Xv staged, P hoisted)

  // ---- phase 6: B1 = Xv @ Mvo -> B1-image [et(16)][kk8(4)][64][8] in Breg
  {
    const bf16x8* wp = reinterpret_cast<const bf16x8*>(mvo);
    bf16x8 vf0[8], vf1[8];
#pragma unroll
    for (int k8 = 0; k8 < 8; ++k8) {
      vf0[k8] = wp[((2 * w)     * 8 + k8) * 64 + lane];
      vf1[k8] = wp[((2 * w + 1) * 8 + k8) * 64 + lane];
    }
#pragma unroll
    for (int ct = 0; ct < 8; ++ct) {
      bf16x8 xf[8];
#pragma unroll
      for (int k8 = 0; k8 < 8; ++k8) {
        int brow = ct * 16 + lr;
        xf[k8] = *reinterpret_cast<const bf16x8*>(
            Areg + brow * 512 + ((k8 * 64 + g * 16) ^ ((brow & 7) << 4)));
      }
      f32x4 a0 = {0.f,0.f,0.f,0.f}, a1 = {0.f,0.f,0.f,0.f};
#pragma unroll
      for (int k8 = 0; k8 < 8; ++k8) {
        a0 = MFMA(vf0[k8], xf[k8], a0);
        a1 = MFMA(vf1[k8], xf[k8], a1);
      }
      int kk8 = ct >> 1;
#pragma unroll
      for (int dth = 0; dth < 2; ++dth) {
        const f32x4& ac = dth ? a1 : a0;
        char* bse = Breg + ((2 * w + dth) * 4 + kk8) * 1024 +
                    (16 * ((ct * 2 + (lr >> 3)) & 3)) * 16 + (lr & 7) * 2;
#pragma unroll
        for (int j = 0; j < 4; ++j)
          *reinterpret_cast<__bf16*>(bse + (4 * g + j) * 16) = (__bf16)ac[j];
      }
    }
  }
  __syncthreads();                               // b6

  // ---- phase 7: out = P @ B1 + bo, direct global stores
  {
    float br[16];
#pragma unroll
    for (int et = 0; et < 16; ++et) br[et] = bo[et * 16 + lr];
#pragma unroll
    for (int et = 0; et < 16; ++et) {
      bf16x8 bfr[4];
#pragma unroll
      for (int kk8 = 0; kk8 < 4; ++kk8)
        bfr[kk8] = *reinterpret_cast<const bf16x8*>(
            Breg + (et * 4 + kk8) * 1024 + lane * 16);
      f32x4 a = {0.f,0.f,0.f,0.f};
#pragma unroll
      for (int kk8 = 0; kk8 < 4; ++kk8) a = MFMA(pa[kk8], bfr[kk8], a);
#pragma unroll
      for (int j = 0; j < 4; ++j) {
        int q = w * 16 + 4 * g + j;
        out[((size_t)n * 8192 + q * 64 + s) * 256 + et * 16 + lr] = a[j] + br[et];
      }
    }
  }
}

extern "C" void kernel_launch(void* const* d_in, const int* in_sizes, int n_in,
                              void* d_out, int out_size, void* d_ws, size_t ws_size,
                              hipStream_t stream) {
  const float* values = (const float*)d_in[0];
  const float* keys   = (const float*)d_in[1];
  const float* query  = (const float*)d_in[2];
  const int*   mask   = (const int*)d_in[3];
  const float* Wq     = (const float*)d_in[4];
  const float* Wk     = (const float*)d_in[5];
  const float* Wv     = (const float*)d_in[6];
  const float* Wo     = (const float*)d_in[7];
  const float* bo     = (const float*)d_in[8];
  float* out = (float*)d_out;

  char* w = (char*)d_ws;
  float*  wosum = (float*)w;  w += 262144;   // [e2][eo] fp32
  __bf16* mqk   = (__bf16*)w; w += 131072;   // pack [16 ct][8 k8][64][8]
  __bf16* mvo   = (__bf16*)w; w += 131072;

  prep_wosum<<<256, 256, 0, stream>>>(Wo, wosum);
  prep_mm<<<dim3(8, 2), 512, 0, stream>>>(Wq, Wk, Wv, wosum, mqk, mvo);
  fused_attn<<<256, 512, 131072, stream>>>(values, keys, query, mask,
                                           mqk, mvo, bo, out);
}

// Round 9
// 55.588 us; speedup vs baseline: 1.0286x; 1.0286x over previous
//
#include <hip/hip_runtime.h>
#include <hip/hip_bf16.h>

// N=4, L=128, S=64, D=256, H=8. Heads collapse; weights pre-compose:
//   Mqk = Wq Wk^T, Mvo = Wv WoSum (WoSum = sum_h Wo_h)
// Per slice sl=n*64+s: T = Xq@Mqk; S = T@Xk^T; P = softmax(S/16+mask);
// B1 = Xv@Mvo; out = P@B1 + bo.
// Round 9: 16-wave (1024-thr) blocks for 4 waves/SIMD occupancy.
//   T: wave w -> Mqk tile dt=w.  S: wave pair (w, w^8) splits k2 halves,
//   softmax joined via 2KB LDS (mx,sum) exchange.  B1: wave w -> Mvo tile et=w.
//   out: wave w -> (qt=w&7, e-half=w>>3) using shared P image.
// Frag convention: [tile][k8][lane(64)][j(8)]: lane l = row/col (l&15),
// k = k8*32+(l>>4)*8+j. A/B share the lane->k map; D row=4*(lane>>4)+j,
// col=lane&15.
// LDS: A [0,64K) staged X (Xq -> Xk -> Xv); B [64K,128K) Timg -> Pimg -> B1img;
//      scr [128K,+2K) softmax pair exchange.

using bf16x4 = __attribute__((ext_vector_type(4))) __bf16;
using bf16x8 = __attribute__((ext_vector_type(8))) __bf16;
using f32x4  = __attribute__((ext_vector_type(4))) float;

#define MFMA(a, b, c) __builtin_amdgcn_mfma_f32_16x16x32_bf16((a), (b), (c), 0, 0, 0)

__device__ __forceinline__ bf16x8 cvt8(float4 f0, float4 f1) {
  bf16x8 a;
  a[0]=(__bf16)f0.x; a[1]=(__bf16)f0.y; a[2]=(__bf16)f0.z; a[3]=(__bf16)f0.w;
  a[4]=(__bf16)f1.x; a[5]=(__bf16)f1.y; a[6]=(__bf16)f1.z; a[7]=(__bf16)f1.w;
  return a;
}

// ---------------------------------------------------------------- prep
// grid (16, 2) x 512. Block (ct, isV). mqk pack from Wq x Wk; mvo pack from
// Wv x WoSum-tile (computed in LDS directly from Wo).
// pack[ct][k8][lane][j]: slot=(lane&15)=out-col idx, k=k8*32+(lane>>4)*8+j.
__global__ __launch_bounds__(512) void prep_mm(
    const float* __restrict__ Wq, const float* __restrict__ Wk,
    const float* __restrict__ Wv, const float* __restrict__ Wo,
    __bf16* __restrict__ mqk, __bf16* __restrict__ mvo) {
  __shared__ float wt[256 * 17];                  // [e2][eol] padded
  const int t = threadIdx.x, lane = t & 63, w = t >> 6;
  const int lr = lane & 15, g = lane >> 4;
  const int ct = blockIdx.x;
  const bool isV = blockIdx.y != 0;
  const float* Aw = isV ? Wv : Wq;
  __bf16* dst = isV ? mvo : mqk;

  bf16x8 af0[8], af1[8];
#pragma unroll
  for (int k8 = 0; k8 < 8; ++k8) {
    const float* p0 = Aw + (size_t)((2 * w)     * 16 + lr) * 256 + k8 * 32 + g * 8;
    const float* p1 = Aw + (size_t)((2 * w + 1) * 16 + lr) * 256 + k8 * 32 + g * 8;
    af0[k8] = cvt8(*(const float4*)p0, *(const float4*)(p0 + 4));
    af1[k8] = cvt8(*(const float4*)p1, *(const float4*)(p1 + 4));
  }
  bf16x8 bf[8];
  if (!isV) {
#pragma unroll
    for (int k8 = 0; k8 < 8; ++k8) {
      const float* p = Wk + (size_t)(ct * 16 + lr) * 256 + k8 * 32 + g * 8;
      bf[k8] = cvt8(*(const float4*)p, *(const float4*)(p + 4));
    }
  } else {
#pragma unroll
    for (int i = 0; i < 8; ++i) {
      int cell = i * 512 + t, e2 = cell >> 4, eol = cell & 15;
      float ssum = 0.f;
#pragma unroll
      for (int h = 0; h < 8; ++h)
        ssum += Wo[((size_t)(h * 256 + e2)) * 256 + ct * 16 + eol];
      wt[e2 * 17 + eol] = ssum;
    }
    __syncthreads();
#pragma unroll
    for (int k8 = 0; k8 < 8; ++k8)
#pragma unroll
      for (int jj = 0; jj < 8; ++jj)
        bf[k8][jj] = (__bf16)wt[(k8 * 32 + g * 8 + jj) * 17 + lr];
  }
  f32x4 a0 = {0.f,0.f,0.f,0.f}, a1 = {0.f,0.f,0.f,0.f};
#pragma unroll
  for (int k8 = 0; k8 < 8; ++k8) {
    a0 = MFMA(af0[k8], bf[k8], a0);
    a1 = MFMA(af1[k8], bf[k8], a1);
  }
#pragma unroll
  for (int rtl = 0; rtl < 2; ++rtl) {
    const f32x4& ac = rtl ? a1 : a0;
    bf16x4 pb;
#pragma unroll
    for (int j = 0; j < 4; ++j) pb[j] = (__bf16)ac[j];
    size_t off = (size_t)ct * 4096 + w * 512 +
                 ((2 * rtl + (g >> 1)) * 16 + lr) * 8 + 4 * (g & 1);
    *reinterpret_cast<bf16x4*>(dst + off) = pb;
  }
}

// ---------------------------------------------------------------- fused
__global__ __launch_bounds__(1024, 4) void fused_attn(
    const float* __restrict__ Xv, const float* __restrict__ Xk,
    const float* __restrict__ Xq, const int* __restrict__ mask,
    const __bf16* __restrict__ mqk, const __bf16* __restrict__ mvo,
    const float* __restrict__ bo, float* __restrict__ out) {
  extern __shared__ char lds[];
  char*  A   = lds;                               // 64KB staging
  char*  B   = lds + 65536;                       // 64KB images
  float* scr = reinterpret_cast<float*>(lds + 131072);  // 2KB
  const int t = threadIdx.x, lane = t & 63, w = t >> 6;  // w 0..15
  const int lr = lane & 15, g = lane >> 4;
  const int sl = blockIdx.x, n = sl >> 6, s = sl & 63;
  const int qt = w & 7, kh = w >> 3;

  auto fill = [&](const float* __restrict__ X, float4* vr) {
#pragma unroll
    for (int i = 0; i < 4; ++i) {
      int f8 = i * 1024 + t, row = f8 >> 5, c8 = f8 & 31;
      const float* src = X + ((size_t)(n * 8192 + row * 64 + s)) * 256 + c8 * 8;
      vr[2 * i]     = *reinterpret_cast<const float4*>(src);
      vr[2 * i + 1] = *reinterpret_cast<const float4*>(src + 4);
    }
  };
  auto flushv = [&](const float4* vr) {
#pragma unroll
    for (int i = 0; i < 4; ++i) {
      int f8 = i * 1024 + t, row = f8 >> 5, c8 = f8 & 31;
      bf16x8 b;
      b[0]=(__bf16)vr[2*i].x;   b[1]=(__bf16)vr[2*i].y;
      b[2]=(__bf16)vr[2*i].z;   b[3]=(__bf16)vr[2*i].w;
      b[4]=(__bf16)vr[2*i+1].x; b[5]=(__bf16)vr[2*i+1].y;
      b[6]=(__bf16)vr[2*i+1].z; b[7]=(__bf16)vr[2*i+1].w;
      *reinterpret_cast<bf16x8*>(
          A + row * 512 + ((c8 * 16) ^ ((row & 7) << 4))) = b;
    }
  };

  // ---- phase 1: Mqk tile loads (latency hoist), stage Xq
  bf16x8 wf[8];
  {
    const bf16x8* wp = reinterpret_cast<const bf16x8*>(mqk);
#pragma unroll
    for (int k8 = 0; k8 < 8; ++k8) wf[k8] = wp[(w * 8 + k8) * 64 + lane];
  }
  {
    float4 vr[8];
    fill(Xq, vr);
    flushv(vr);
  }
  __syncthreads();                               // b1

  // ---- phase 2: T = Xq@Mqk, wave w -> dt=w; prefetch Xk
  float4 vrp[8];
  fill(Xk, vrp);
#pragma unroll
  for (int ct = 0; ct < 8; ++ct) {
    bf16x8 xf[8];
#pragma unroll
    for (int k8 = 0; k8 < 8; ++k8) {
      int brow = ct * 16 + lr;
      xf[k8] = *reinterpret_cast<const bf16x8*>(
          A + brow * 512 + ((k8 * 64 + g * 16) ^ ((brow & 7) << 4)));
    }
    f32x4 a = {0.f,0.f,0.f,0.f};
#pragma unroll
    for (int k8 = 0; k8 < 8; ++k8) a = MFMA(wf[k8], xf[k8], a);
    bf16x4 pb;
#pragma unroll
    for (int j = 0; j < 4; ++j) pb[j] = (__bf16)a[j];
    *reinterpret_cast<bf16x4*>(
        B + ct * 8192 + (w >> 1) * 1024 +
        (lr + 16 * (2 * (w & 1) + (g >> 1))) * 16 + (g & 1) * 8) = pb;
  }
  __syncthreads();                               // b2

  // ---- phase 3: hoist T A-frags for qt; stage Xk
  bf16x8 af[8];
#pragma unroll
  for (int k8 = 0; k8 < 8; ++k8)
    af[k8] = *reinterpret_cast<const bf16x8*>(B + qt * 8192 + k8 * 1024 + lane * 16);
  flushv(vrp);
  __syncthreads();                               // b3

  // ---- phase 4: S half (wave w: qt, k2-tiles kh*4..+3); prefetch Xv + mask
  fill(Xv, vrp);
  int mreg[4][4];
#pragma unroll
  for (int ct = 0; ct < 4; ++ct)
#pragma unroll
    for (int j = 0; j < 4; ++j)
      mreg[ct][j] = mask[((size_t)n * 128 + qt * 16 + 4 * g + j) * 128 +
                         (kh * 4 + ct) * 16 + lr];
  f32x4 sacc[4];
#pragma unroll
  for (int ct = 0; ct < 4; ++ct) {
    int brow = (kh * 4 + ct) * 16 + lr;
    bf16x8 xf[8];
#pragma unroll
    for (int k8 = 0; k8 < 8; ++k8)
      xf[k8] = *reinterpret_cast<const bf16x8*>(
          A + brow * 512 + ((k8 * 64 + g * 16) ^ ((brow & 7) << 4)));
    f32x4 a = {0.f,0.f,0.f,0.f};
#pragma unroll
    for (int k8 = 0; k8 < 8; ++k8) a = MFMA(af[k8], xf[k8], a);
    sacc[ct] = a;
  }

  // partial softmax over this wave's 64 k2
  float p[4][4], mxv[4], smv[4];
#pragma unroll
  for (int j = 0; j < 4; ++j) {
    float mx = -3e38f;
#pragma unroll
    for (int ct = 0; ct < 4; ++ct) {
      float sv = mreg[ct][j] ? sacc[ct][j] * 0.0625f : -6.25e18f;  // -1e20/16
      p[ct][j] = sv;
      mx = fmaxf(mx, sv);
    }
#pragma unroll
    for (int o = 1; o < 16; o <<= 1) mx = fmaxf(mx, __shfl_xor(mx, o));
    float sum = 0.f;
#pragma unroll
    for (int ct = 0; ct < 4; ++ct) {
      float e = __expf(p[ct][j] - mx);
      p[ct][j] = e;
      sum += e;
    }
#pragma unroll
    for (int o = 1; o < 16; o <<= 1) sum += __shfl_xor(sum, o);
    mxv[j] = mx; smv[j] = sum;
  }
  if (lr == 0) {
#pragma unroll
    for (int j = 0; j < 4; ++j) {
      scr[w * 32 + g * 8 + j * 2]     = mxv[j];
      scr[w * 32 + g * 8 + j * 2 + 1] = smv[j];
    }
  }
  __syncthreads();                               // b4 (also: all S-reads done)

  // ---- phase 5: combine with partner half, write P image, stage Xv
  {
    int pw = w ^ 8;
#pragma unroll
    for (int j = 0; j < 4; ++j) {
      float pmx = scr[pw * 32 + g * 8 + j * 2];
      float psm = scr[pw * 32 + g * 8 + j * 2 + 1];
      float M = fmaxf(mxv[j], pmx);
      float tot = smv[j] * __expf(mxv[j] - M) + psm * __expf(pmx - M);
      float scale = __expf(mxv[j] - M) / tot;
#pragma unroll
      for (int ct = 0; ct < 4; ++ct) p[ct][j] *= scale;
    }
  }
#pragma unroll
  for (int ct = 0; ct < 4; ++ct) {
    int cg = kh * 4 + ct;
    char* bse = B + qt * 4096 + (cg >> 1) * 1024 +
                (16 * ((cg * 2 + (lr >> 3)) & 3)) * 16 + (lr & 7) * 2;
#pragma unroll
    for (int j = 0; j < 4; ++j)
      *reinterpret_cast<__bf16*>(bse + (4 * g + j) * 16) = (__bf16)p[ct][j];
  }
  flushv(vrp);                                   // Xv -> A (safe: b4 passed)
  __syncthreads();                               // b5

  // ---- phase 6: Mvo tile loads + hoist P A-frags
  bf16x8 vf[8];
  {
    const bf16x8* wp = reinterpret_cast<const bf16x8*>(mvo);
#pragma unroll
    for (int k8 = 0; k8 < 8; ++k8) vf[k8] = wp[(w * 8 + k8) * 64 + lane];
  }
  bf16x8 pa[4];
#pragma unroll
  for (int kk8 = 0; kk8 < 4; ++kk8)
    pa[kk8] = *reinterpret_cast<const bf16x8*>(B + qt * 4096 + kk8 * 1024 + lane * 16);
  __syncthreads();                               // b6

  // ---- phase 7: B1 = Xv@Mvo, wave w -> et=w; bias prefetch
  float br[8];
#pragma unroll
  for (int e8 = 0; e8 < 8; ++e8) br[e8] = bo[(kh * 8 + e8) * 16 + lr];
#pragma unroll
  for (int ct = 0; ct < 8; ++ct) {
    int brow = ct * 16 + lr;
    bf16x8 xf[8];
#pragma unroll
    for (int k8 = 0; k8 < 8; ++k8)
      xf[k8] = *reinterpret_cast<const bf16x8*>(
          A + brow * 512 + ((k8 * 64 + g * 16) ^ ((brow & 7) << 4)));
    f32x4 a = {0.f,0.f,0.f,0.f};
#pragma unroll
    for (int k8 = 0; k8 < 8; ++k8) a = MFMA(vf[k8], xf[k8], a);
    char* bse = B + w * 4096 + (ct >> 1) * 1024 +
                (16 * ((ct * 2 + (lr >> 3)) & 3)) * 16 + (lr & 7) * 2;
#pragma unroll
    for (int j = 0; j < 4; ++j)
      *reinterpret_cast<__bf16*>(bse + (4 * g + j) * 16) = (__bf16)a[j];
  }
  __syncthreads();                               // b7

  // ---- phase 8: out = P@B1 + bo (wave w: qt, e-tiles kh*8..+7)
#pragma unroll
  for (int e8 = 0; e8 < 8; ++e8) {
    int et = kh * 8 + e8;
    bf16x8 bfr[4];
#pragma unroll
    for (int kk8 = 0; kk8 < 4; ++kk8)
      bfr[kk8] = *reinterpret_cast<const bf16x8*>(
          B + et * 4096 + kk8 * 1024 + lane * 16);
    f32x4 a = {0.f,0.f,0.f,0.f};
#pragma unroll
    for (int kk8 = 0; kk8 < 4; ++kk8) a = MFMA(pa[kk8], bfr[kk8], a);
#pragma unroll
    for (int j = 0; j < 4; ++j) {
      int q = qt * 16 + 4 * g + j;
      out[((size_t)n * 8192 + q * 64 + s) * 256 + et * 16 + lr] = a[j] + br[e8];
    }
  }
}

extern "C" void kernel_launch(void* const* d_in, const int* in_sizes, int n_in,
                              void* d_out, int out_size, void* d_ws, size_t ws_size,
                              hipStream_t stream) {
  const float* values = (const float*)d_in[0];
  const float* keys   = (const float*)d_in[1];
  const float* query  = (const float*)d_in[2];
  const int*   mask   = (const int*)d_in[3];
  const float* Wq     = (const float*)d_in[4];
  const float* Wk     = (const float*)d_in[5];
  const float* Wv     = (const float*)d_in[6];
  const float* Wo     = (const float*)d_in[7];
  const float* bo     = (const float*)d_in[8];
  float* out = (float*)d_out;

  char* w = (char*)d_ws;
  __bf16* mqk = (__bf16*)w; w += 131072;   // pack [16 ct][8 k8][64][8]
  __bf16* mvo = (__bf16*)w; w += 131072;

  prep_mm<<<dim3(16, 2), 512, 0, stream>>>(Wq, Wk, Wv, Wo, mqk, mvo);
  fused_attn<<<256, 1024, 133120, stream>>>(values, keys, query, mask,
                                            mqk, mvo, bo, out);
}

// Round 10
// 54.128 us; speedup vs baseline: 1.0564x; 1.0270x over previous
//
#include <hip/hip_runtime.h>
#include <hip/hip_bf16.h>

// N=4, L=128, S=64, D=256, H=8. Heads collapse; weights pre-compose:
//   Mqk = Wq Wk^T, Mvo = Wv WoSum (WoSum = sum_h Wo_h)
// Per slice sl=n*64+s: T = Xq@Mqk; S = T@Xk^T; P = softmax(S/16+mask);
// B1 = Xv@Mvo; out = P@B1 + bo.  One block (512 thr / 8 waves, 160KB LDS)/slice.
//
// Round 10: all GEMMs on mfma_f32_32x32x16_bf16 (halves LDS bytes+instrs per
// FLOP vs 16x16x32). Frag convention (A and B): lane l -> row l&31,
// k = (l>>5)*8 + j. D: col = lane&31, row(reg) = (reg&3)+8*(reg>>2)+4*(l>>5).
// Operand order per phase chosen so D's lane-axis == the consumer image's
// frag-lane axis => image writes are contiguous b64 (conflict-free):
//   T:  mfma(Mqk, Xq)  D[dout][q]   -> Timg  (S's B... frag-lane=q)
//   S:  mfma(Xk, T)    D[k2][q]     -> softmax per-lane over regs (swapped-S)
//                                      P-image frag-lane=q == D lane  ✓
//   B1: mfma(Xv, Mvo)  D[k2][e]     -> B1img frag-lane=e == D lane   ✓
//   out:mfma(B1, P)    D[e][q]      -> regs->e => float4 global stores ✓
// Pack granule: [tile32][ks][slot=row+32*khalf][16B: j*2 (+hl*8 by writer)].
// LDS: A [0,64K) staged X (Xq->Xk->Xv, row*512, 16B-chunk XOR swizzle)
//      Timg [64K,128K) (dead after af hoist) ; Pimg [64K,96K) ; B1img+scr [96K,160K)

using bf16x4 = __attribute__((ext_vector_type(4))) __bf16;
using bf16x8 = __attribute__((ext_vector_type(8))) __bf16;
using f32x16 = __attribute__((ext_vector_type(16))) float;

#define MFMA32(a, b, c) __builtin_amdgcn_mfma_f32_32x32x16_bf16((a), (b), (c), 0, 0, 0)

__device__ __forceinline__ bf16x8 cvt8(float4 f0, float4 f1) {
  bf16x8 a;
  a[0]=(__bf16)f0.x; a[1]=(__bf16)f0.y; a[2]=(__bf16)f0.z; a[3]=(__bf16)f0.w;
  a[4]=(__bf16)f1.x; a[5]=(__bf16)f1.y; a[6]=(__bf16)f1.z; a[7]=(__bf16)f1.w;
  return a;
}
__device__ __forceinline__ f32x16 zero16() {
  f32x16 z;
#pragma unroll
  for (int j = 0; j < 16; ++j) z[j] = 0.f;
  return z;
}

// ---------------------------------------------------------------- prep
// grid (8 ct, 2 isV) x 512thr. Block ct = out-col tile (dout/eo), wave w = dt
// (din/dv tile). mqk[din][dout] = sum_e Wq[din][e]Wk[dout][e];
// mvo[dv][eo] = sum_e2 Wv[dv][e2] WoSum[e2][eo] (WoSum 32-col tile in LDS).
__global__ __launch_bounds__(512) void prep_pack(
    const float* __restrict__ Wq, const float* __restrict__ Wk,
    const float* __restrict__ Wv, const float* __restrict__ Wo,
    __bf16* __restrict__ mqk, __bf16* __restrict__ mvo) {
  __shared__ float wt[256 * 33];
  const int t = threadIdx.x, lane = t & 63, w = t >> 6;
  const int lq = lane & 31, hl = lane >> 5;
  const int ct = blockIdx.x;
  const bool isV = blockIdx.y != 0;
  if (isV) {
#pragma unroll
    for (int i = 0; i < 16; ++i) {
      int cell = i * 512 + t;
      int e2 = cell >> 5, eol = cell & 31;
      float ssum = 0.f;
#pragma unroll
      for (int h = 0; h < 8; ++h)
        ssum += Wo[((size_t)(h * 256 + e2)) * 256 + ct * 32 + eol];
      wt[e2 * 33 + eol] = ssum;
    }
    __syncthreads();
  }
  const float* Aw = isV ? Wv : Wq;
  bf16x8 afr[16], bfr[16];
#pragma unroll
  for (int ks = 0; ks < 16; ++ks) {
    const float* p = Aw + (size_t)(w * 32 + lq) * 256 + ks * 16 + hl * 8;
    afr[ks] = cvt8(*(const float4*)p, *(const float4*)(p + 4));
  }
  if (!isV) {
#pragma unroll
    for (int ks = 0; ks < 16; ++ks) {
      const float* p = Wk + (size_t)(ct * 32 + lq) * 256 + ks * 16 + hl * 8;
      bfr[ks] = cvt8(*(const float4*)p, *(const float4*)(p + 4));
    }
  } else {
#pragma unroll
    for (int ks = 0; ks < 16; ++ks)
#pragma unroll
      for (int jj = 0; jj < 8; ++jj)
        bfr[ks][jj] = (__bf16)wt[(ks * 16 + hl * 8 + jj) * 33 + lq];
  }
  f32x16 acc = zero16();
#pragma unroll
  for (int ks = 0; ks < 16; ++ks) acc = MFMA32(afr[ks], bfr[ks], acc);
  // D[i=din/dv (regs)][j=dout/eo (lane)] -> pack[ct][ks=2w+(a>>1)][slot][j]
  char* dstb = (char*)(isV ? mvo : mqk);
#pragma unroll
  for (int a = 0; a < 4; ++a) {
    bf16x4 v;
#pragma unroll
    for (int j = 0; j < 4; ++j) v[j] = (__bf16)acc[4 * a + j];
    *(bf16x4*)(dstb + ct * 16384 + (2 * w + (a >> 1)) * 1024 +
               (lq + 32 * (a & 1)) * 16 + hl * 8) = v;
  }
}

// ---------------------------------------------------------------- fused
__global__ __launch_bounds__(512) void fused_attn(
    const float* __restrict__ Xv, const float* __restrict__ Xk,
    const float* __restrict__ Xq, const int* __restrict__ mask,
    const __bf16* __restrict__ mqk, const __bf16* __restrict__ mvo,
    const float* __restrict__ bo, float* __restrict__ out) {
  extern __shared__ char lds[];
  char* A     = lds;                 // 64KB staged X
  char* Timg  = lds + 65536;         // 64KB (dead after af hoist)
  char* Pimg  = lds + 65536;         // 32KB (reuses Timg low)
  char* B1img = lds + 98304;         // 64KB
  float* scr  = (float*)(lds + 98304);  // 2KB transient (before B1 writes)
  const int t = threadIdx.x, lane = t & 63, w = t >> 6;
  const int lq = lane & 31, hl = lane >> 5;
  const int qt = w & 3, kh = w >> 2;          // S/out roles
  const int sl = blockIdx.x, n = sl >> 6, s = sl & 63;

  auto fill = [&](const float* __restrict__ X, float4* vr) {
#pragma unroll
    for (int i = 0; i < 8; ++i) {
      int f8 = i * 512 + t, row = f8 >> 5, c8 = f8 & 31;
      const float* src = X + ((size_t)(n * 8192 + row * 64 + s)) * 256 + c8 * 8;
      vr[2 * i]     = *reinterpret_cast<const float4*>(src);
      vr[2 * i + 1] = *reinterpret_cast<const float4*>(src + 4);
    }
  };
  auto flushv = [&](const float4* vr) {
#pragma unroll
    for (int i = 0; i < 8; ++i) {
      int f8 = i * 512 + t, row = f8 >> 5, c8 = f8 & 31;
      bf16x8 b;
      b[0]=(__bf16)vr[2*i].x;   b[1]=(__bf16)vr[2*i].y;
      b[2]=(__bf16)vr[2*i].z;   b[3]=(__bf16)vr[2*i].w;
      b[4]=(__bf16)vr[2*i+1].x; b[5]=(__bf16)vr[2*i+1].y;
      b[6]=(__bf16)vr[2*i+1].z; b[7]=(__bf16)vr[2*i+1].w;
      *reinterpret_cast<bf16x8*>(A + row * 512 + ((c8 * 16) ^ ((row & 7) << 4))) = b;
    }
  };
  auto xfrag = [&](int brow, int ks) -> bf16x8 {
    return *reinterpret_cast<const bf16x8*>(
        A + brow * 512 + ((ks * 32 + hl * 16) ^ ((brow & 7) << 4)));
  };

  // ---- phase 1: stage Xq
  { float4 vr[16]; fill(Xq, vr); flushv(vr); }
  __syncthreads();                               // b1

  // ---- phase 2: T = Xq@Mqk, wave w = dout-tile; prefetch Xk
  float4 vrp[16];
  fill(Xk, vrp);
  {
    const bf16x8* wp = reinterpret_cast<const bf16x8*>(mqk);
    bf16x8 wf[16];
#pragma unroll
    for (int ks = 0; ks < 16; ++ks) wf[ks] = wp[(w * 16 + ks) * 64 + lane];
#pragma unroll
    for (int rt = 0; rt < 4; ++rt) {
      f32x16 acc = zero16();
#pragma unroll
      for (int ks = 0; ks < 16; ++ks)
        acc = MFMA32(wf[ks], xfrag(rt * 32 + lq, ks), acc);
#pragma unroll
      for (int a = 0; a < 4; ++a) {
        bf16x4 v;
#pragma unroll
        for (int j = 0; j < 4; ++j) v[j] = (__bf16)acc[4 * a + j];
        *(bf16x4*)(Timg + rt * 16384 + (2 * w + (a >> 1)) * 1024 +
                   (lq + 32 * (a & 1)) * 16 + hl * 8) = v;
      }
    }
  }
  __syncthreads();                               // b2

  // ---- phase 3: hoist T B-frags (lane->q) for qt; stage Xk
  bf16x8 af[16];
#pragma unroll
  for (int ks = 0; ks < 16; ++ks)
    af[ks] = *reinterpret_cast<const bf16x8*>(Timg + qt * 16384 + ks * 1024 + lane * 16);
  flushv(vrp);
  __syncthreads();                               // b3

  // ---- phase 4: S = Xk x T (swapped: lane->q, regs->k2); prefetch Xv + mask
  fill(Xv, vrp);
  int ms[2][16];
#pragma unroll
  for (int c = 0; c < 2; ++c)
#pragma unroll
    for (int a = 0; a < 4; ++a) {
      int4 m = *reinterpret_cast<const int4*>(
          mask + ((size_t)n * 128 + qt * 32 + lq) * 128 +
          (2 * kh + c) * 32 + 8 * a + 4 * hl);
      ms[c][4*a] = m.x; ms[c][4*a+1] = m.y; ms[c][4*a+2] = m.z; ms[c][4*a+3] = m.w;
    }
  f32x16 acc[2];
#pragma unroll
  for (int c = 0; c < 2; ++c) {
    acc[c] = zero16();
    int kt = 2 * kh + c;
#pragma unroll
    for (int ks = 0; ks < 16; ++ks)
      acc[c] = MFMA32(xfrag(kt * 32 + lq, ks), af[ks], acc[c]);
  }
  // masked scale, per-lane softmax partials over the 32 reg-values
  float mx = -3e38f;
#pragma unroll
  for (int c = 0; c < 2; ++c)
#pragma unroll
    for (int r = 0; r < 16; ++r) {
      float sv = ms[c][r] ? acc[c][r] * 0.0625f : -6.25e18f;  // -1e20/16
      acc[c][r] = sv;
      mx = fmaxf(mx, sv);
    }
  mx = fmaxf(mx, __shfl_xor(mx, 32));            // join hl halves (same q)
  float sum = 0.f;
#pragma unroll
  for (int c = 0; c < 2; ++c)
#pragma unroll
    for (int r = 0; r < 16; ++r) {
      float e = __expf(acc[c][r] - mx);
      acc[c][r] = e;
      sum += e;
    }
  sum += __shfl_xor(sum, 32);
  if (lane < 32) {
    float2* s2 = reinterpret_cast<float2*>(scr);
    s2[(qt * 2 + kh) * 32 + lane] = make_float2(mx, sum);
  }
  __syncthreads();                               // b4

  // ---- phase 5: pair-combine, write P image, stage Xv, prefetch Mvo
  {
    float2 pr = reinterpret_cast<const float2*>(scr)[(qt * 2 + (kh ^ 1)) * 32 + lq];
    float M = fmaxf(mx, pr.x);
    float tot = sum * __expf(mx - M) + pr.y * __expf(pr.x - M);
    float scale = __expf(mx - M) / tot;
#pragma unroll
    for (int c = 0; c < 2; ++c)
#pragma unroll
      for (int r = 0; r < 16; ++r) acc[c][r] *= scale;
  }
#pragma unroll
  for (int c = 0; c < 2; ++c)
#pragma unroll
    for (int a = 0; a < 4; ++a) {
      bf16x4 v;
#pragma unroll
      for (int j = 0; j < 4; ++j) v[j] = (__bf16)acc[c][4 * a + j];
      *(bf16x4*)(Pimg + qt * 8192 + ((2 * kh + c) * 2 + (a >> 1)) * 1024 +
                 (lq + 32 * (a & 1)) * 16 + hl * 8) = v;
    }
  flushv(vrp);                                   // Xv -> A
  bf16x8 vf[16];
  {
    const bf16x8* vp = reinterpret_cast<const bf16x8*>(mvo);
#pragma unroll
    for (int ks = 0; ks < 16; ++ks) vf[ks] = vp[(w * 16 + ks) * 64 + lane];
  }
  __syncthreads();                               // b5

  // ---- phase 6: B1 = Xv x Mvo (lane->e, regs->k2), wave w = e-tile
#pragma unroll
  for (int rt = 0; rt < 4; ++rt) {
    f32x16 a1 = zero16();
#pragma unroll
    for (int ks = 0; ks < 16; ++ks)
      a1 = MFMA32(xfrag(rt * 32 + lq, ks), vf[ks], a1);
#pragma unroll
    for (int a = 0; a < 4; ++a) {
      bf16x4 v;
#pragma unroll
      for (int j = 0; j < 4; ++j) v[j] = (__bf16)a1[4 * a + j];
      *(bf16x4*)(B1img + w * 8192 + (2 * rt + (a >> 1)) * 1024 +
                 (lq + 32 * (a & 1)) * 16 + hl * 8) = v;
    }
  }
  __syncthreads();                               // b6

  // ---- phase 7: out = B1 x P (lane->q, regs->e) + bo, float4 stores
  bf16x8 pa[8];
#pragma unroll
  for (int ks = 0; ks < 8; ++ks)
    pa[ks] = *reinterpret_cast<const bf16x8*>(Pimg + qt * 8192 + ks * 1024 + lane * 16);
  float* orow = out + ((size_t)(n * 8192) + (qt * 32 + lq) * 64 + s) * 256;
#pragma unroll
  for (int el = 0; el < 4; ++el) {
    int et = kh * 4 + el;
    f32x16 a2 = zero16();
#pragma unroll
    for (int ks = 0; ks < 8; ++ks) {
      bf16x8 bfr = *reinterpret_cast<const bf16x8*>(
          B1img + et * 8192 + ks * 1024 + lane * 16);
      a2 = MFMA32(bfr, pa[ks], a2);
    }
#pragma unroll
    for (int a = 0; a < 4; ++a) {
      float4 bv = *reinterpret_cast<const float4*>(bo + et * 32 + 8 * a + 4 * hl);
      float4 st;
      st.x = a2[4*a]   + bv.x; st.y = a2[4*a+1] + bv.y;
      st.z = a2[4*a+2] + bv.z; st.w = a2[4*a+3] + bv.w;
      *reinterpret_cast<float4*>(orow + et * 32 + 8 * a + 4 * hl) = st;
    }
  }
}

extern "C" void kernel_launch(void* const* d_in, const int* in_sizes, int n_in,
                              void* d_out, int out_size, void* d_ws, size_t ws_size,
                              hipStream_t stream) {
  const float* values = (const float*)d_in[0];
  const float* keys   = (const float*)d_in[1];
  const float* query  = (const float*)d_in[2];
  const int*   mask   = (const int*)d_in[3];
  const float* Wq     = (const float*)d_in[4];
  const float* Wk     = (const float*)d_in[5];
  const float* Wv     = (const float*)d_in[6];
  const float* Wo     = (const float*)d_in[7];
  const float* bo     = (const float*)d_in[8];
  float* out = (float*)d_out;

  char* w = (char*)d_ws;
  __bf16* mqk = (__bf16*)w; w += 131072;   // pack [8 ct32][16 ks][64][8]
  __bf16* mvo = (__bf16*)w; w += 131072;

  prep_pack<<<dim3(8, 2), 512, 0, stream>>>(Wq, Wk, Wv, Wo, mqk, mvo);
  fused_attn<<<256, 512, 163840, stream>>>(values, keys, query, mask,
                                           mqk, mvo, bo, out);
}

// Round 11
// 53.708 us; speedup vs baseline: 1.0646x; 1.0078x over previous
//
#include <hip/hip_runtime.h>
#include <hip/hip_bf16.h>

// N=4, L=128, S=64, D=256, H=8. Heads collapse; weights pre-compose:
//   Mqk = Wq Wk^T, Mvo = Wv WoSum (WoSum = sum_h Wo_h)
// Per slice sl=n*64+s: T = Xq@Mqk; S = T@Xk^T; P = softmax(S/16+mask);
// B1 = Xv@Mvo; out = P@B1 + bo.  One block (512 thr / 8 waves)/slice.
// All GEMMs mfma_f32_32x32x16_bf16. Frags: lane l -> row l&31, k=(l>>5)*8+j.
// D: col=lane&31, row(reg)=(r&3)+8*(r>>2)+4*(l>>5)  [HW-verified].
// Round 11: B1 kept in registers (reg-reshape via pk+shfl_xor(32)); P image
// written as b128 frags via same reshape; mask pre-packed to bits; 5 barriers.
// Reshape algebra (verified against the r10 Pimg encode, which passed):
//   frag chunk ks (k2 = ks*16 + hl*8 + j) <- D-reg r=(j&3)+4*(2*s16+hl_dst)
//   taken from lane-half (j>>2); s16 = ks&1 within a 32-wide rt/kt tile.
// LDS: A [0,64K) staged X (Xq->Xk->Xv); B [64K,128K) Timg -> Pimg(low 32K);
//      scr at B+32K..+34K (Timg-high, dead after af hoist).

using bf16x4 = __attribute__((ext_vector_type(4))) __bf16;
using bf16x8 = __attribute__((ext_vector_type(8))) __bf16;
using f32x16 = __attribute__((ext_vector_type(16))) float;

#define MFMA32(a, b, c) __builtin_amdgcn_mfma_f32_32x32x16_bf16((a), (b), (c), 0, 0, 0)

__device__ __forceinline__ bf16x8 cvt8(float4 f0, float4 f1) {
  bf16x8 a;
  a[0]=(__bf16)f0.x; a[1]=(__bf16)f0.y; a[2]=(__bf16)f0.z; a[3]=(__bf16)f0.w;
  a[4]=(__bf16)f1.x; a[5]=(__bf16)f1.y; a[6]=(__bf16)f1.z; a[7]=(__bf16)f1.w;
  return a;
}
__device__ __forceinline__ f32x16 zero16() {
  f32x16 z;
#pragma unroll
  for (int j = 0; j < 16; ++j) z[j] = 0.f;
  return z;
}
__device__ __forceinline__ unsigned pk(float a, float b) {
  union { __bf16 h[2]; unsigned u; } x;
  x.h[0] = (__bf16)a; x.h[1] = (__bf16)b;
  return x.u;
}
__device__ __forceinline__ bf16x8 u4frag(uint4 w) {
  union { uint4 u; bf16x8 f; } x;
  x.u = w;
  return x.f;
}
// Build one A/B-side frag chunk from 8 consecutive D-regs (base = 8*s16) of a
// 32-wide tile: own half + partner half via shfl_xor(32). hl = lane>>5.
__device__ __forceinline__ uint4 mkfrag(const float* a8, int hl) {
  unsigned p00 = pk(a8[0], a8[1]), p01 = pk(a8[2], a8[3]);
  unsigned p10 = pk(a8[4], a8[5]), p11 = pk(a8[6], a8[7]);
  unsigned r0 = __shfl_xor((int)(hl ? p00 : p10), 32);
  unsigned r1 = __shfl_xor((int)(hl ? p01 : p11), 32);
  uint4 w;
  w.x = hl ? r0 : p00;  w.y = hl ? r1 : p01;
  w.z = hl ? p10 : r0;  w.w = hl ? p11 : r1;
  return w;
}

// ---------------------------------------------------------------- prep
// grid (8 ct, 2 isV) x 512thr. Packs Mqk/Mvo (pack[ct][ks][lane][j], slot=
// out-col, k=contraction) + mask bitwords (isV=0 blocks).
__global__ __launch_bounds__(512) void prep_pack(
    const float* __restrict__ Wq, const float* __restrict__ Wk,
    const float* __restrict__ Wv, const float* __restrict__ Wo,
    const int* __restrict__ mask,
    __bf16* __restrict__ mqk, __bf16* __restrict__ mvo,
    unsigned* __restrict__ mbits) {
  __shared__ float wt[256 * 33];
  const int t = threadIdx.x, lane = t & 63, w = t >> 6;
  const int lq = lane & 31, hl = lane >> 5;
  const int ct = blockIdx.x;
  const bool isV = blockIdx.y != 0;
  if (!isV) {
    int gid = ct * 512 + t;                       // [0,4096)
    if (gid < 2048) {                             // word gid covers mask[gid*32..+32)
      const int* mrow = mask + gid * 32;
      unsigned mw = 0;
#pragma unroll
      for (int b = 0; b < 32; ++b) mw |= (mrow[b] != 0 ? 1u : 0u) << b;
      mbits[gid] = mw;
    }
  } else {
#pragma unroll
    for (int i = 0; i < 16; ++i) {
      int cell = i * 512 + t;
      int e2 = cell >> 5, eol = cell & 31;
      float ssum = 0.f;
#pragma unroll
      for (int h = 0; h < 8; ++h)
        ssum += Wo[((size_t)(h * 256 + e2)) * 256 + ct * 32 + eol];
      wt[e2 * 33 + eol] = ssum;
    }
    __syncthreads();
  }
  const float* Aw = isV ? Wv : Wq;
  bf16x8 afr[16], bfr[16];
#pragma unroll
  for (int ks = 0; ks < 16; ++ks) {
    const float* p = Aw + (size_t)(w * 32 + lq) * 256 + ks * 16 + hl * 8;
    afr[ks] = cvt8(*(const float4*)p, *(const float4*)(p + 4));
  }
  if (!isV) {
#pragma unroll
    for (int ks = 0; ks < 16; ++ks) {
      const float* p = Wk + (size_t)(ct * 32 + lq) * 256 + ks * 16 + hl * 8;
      bfr[ks] = cvt8(*(const float4*)p, *(const float4*)(p + 4));
    }
  } else {
#pragma unroll
    for (int ks = 0; ks < 16; ++ks)
#pragma unroll
      for (int jj = 0; jj < 8; ++jj)
        bfr[ks][jj] = (__bf16)wt[(ks * 16 + hl * 8 + jj) * 33 + lq];
  }
  f32x16 acc = zero16();
#pragma unroll
  for (int ks = 0; ks < 16; ++ks) acc = MFMA32(afr[ks], bfr[ks], acc);
  char* dstb = (char*)(isV ? mvo : mqk);
#pragma unroll
  for (int a = 0; a < 4; ++a) {
    bf16x4 v;
#pragma unroll
    for (int j = 0; j < 4; ++j) v[j] = (__bf16)acc[4 * a + j];
    *(bf16x4*)(dstb + ct * 16384 + (2 * w + (a >> 1)) * 1024 +
               (lq + 32 * (a & 1)) * 16 + hl * 8) = v;
  }
}

// ---------------------------------------------------------------- fused
__global__ __launch_bounds__(512) void fused_attn(
    const float* __restrict__ Xv, const float* __restrict__ Xk,
    const float* __restrict__ Xq, const unsigned* __restrict__ mbits,
    const __bf16* __restrict__ mqk, const __bf16* __restrict__ mvo,
    const float* __restrict__ bo, float* __restrict__ out) {
  extern __shared__ char lds[];
  char* A     = lds;                 // 64KB staged X
  char* Timg  = lds + 65536;         // 64KB (dead after af hoist)
  char* Pimg  = lds + 65536;         // 32KB (reuses Timg low)
  float* scr  = (float*)(lds + 98304);  // 2KB (Timg high, dead post-b3)
  const int t = threadIdx.x, lane = t & 63, w = t >> 6;
  const int lq = lane & 31, hl = lane >> 5;
  const int qt = w & 3, kh = w >> 2;
  const int sl = blockIdx.x, n = sl >> 6, s = sl & 63;

  auto fill = [&](const float* __restrict__ X, float4* vr) {
#pragma unroll
    for (int i = 0; i < 8; ++i) {
      int f8 = i * 512 + t, row = f8 >> 5, c8 = f8 & 31;
      const float* src = X + ((size_t)(n * 8192 + row * 64 + s)) * 256 + c8 * 8;
      vr[2 * i]     = *reinterpret_cast<const float4*>(src);
      vr[2 * i + 1] = *reinterpret_cast<const float4*>(src + 4);
    }
  };
  auto flushv = [&](const float4* vr) {
#pragma unroll
    for (int i = 0; i < 8; ++i) {
      int f8 = i * 512 + t, row = f8 >> 5, c8 = f8 & 31;
      bf16x8 b;
      b[0]=(__bf16)vr[2*i].x;   b[1]=(__bf16)vr[2*i].y;
      b[2]=(__bf16)vr[2*i].z;   b[3]=(__bf16)vr[2*i].w;
      b[4]=(__bf16)vr[2*i+1].x; b[5]=(__bf16)vr[2*i+1].y;
      b[6]=(__bf16)vr[2*i+1].z; b[7]=(__bf16)vr[2*i+1].w;
      *reinterpret_cast<bf16x8*>(A + row * 512 + ((c8 * 16) ^ ((row & 7) << 4))) = b;
    }
  };
  auto xfrag = [&](int brow, int ks) -> bf16x8 {
    return *reinterpret_cast<const bf16x8*>(
        A + brow * 512 + ((ks * 32 + hl * 16) ^ ((brow & 7) << 4)));
  };

  // prologue: Mqk tile loads issued early
  bf16x8 wf[16];
  {
    const bf16x8* wp = reinterpret_cast<const bf16x8*>(mqk);
#pragma unroll
    for (int ks = 0; ks < 16; ++ks) wf[ks] = wp[(w * 16 + ks) * 64 + lane];
  }
  // ---- phase 1: stage Xq
  { float4 vr[16]; fill(Xq, vr); flushv(vr); }
  __syncthreads();                               // b1

  // ---- phase 2: T = Xq@Mqk (wave w = dout-tile); prefetch Xk
  float4 vrp[16];
  fill(Xk, vrp);
#pragma unroll
  for (int rt = 0; rt < 4; ++rt) {
    f32x16 acc = zero16();
#pragma unroll
    for (int ks = 0; ks < 16; ++ks)
      acc = MFMA32(wf[ks], xfrag(rt * 32 + lq, ks), acc);
#pragma unroll
    for (int a = 0; a < 4; ++a) {
      bf16x4 v;
#pragma unroll
      for (int j = 0; j < 4; ++j) v[j] = (__bf16)acc[4 * a + j];
      *(bf16x4*)(Timg + rt * 16384 + (2 * w + (a >> 1)) * 1024 +
                 (lq + 32 * (a & 1)) * 16 + hl * 8) = v;
    }
  }
  __syncthreads();                               // b2

  // ---- phase 3: hoist T B-frags (lane->q) for qt; stage Xk
  bf16x8 af[16];
#pragma unroll
  for (int ks = 0; ks < 16; ++ks)
    af[ks] = *reinterpret_cast<const bf16x8*>(Timg + qt * 16384 + ks * 1024 + lane * 16);
  flushv(vrp);
  __syncthreads();                               // b3

  // ---- phase 4: S = Xk x T (swapped: lane->q, regs->k2); prefetch Xv
  fill(Xv, vrp);
  unsigned mw0 = mbits[((size_t)n * 128 + qt * 32 + lq) * 4 + 2 * kh];
  unsigned mw1 = mbits[((size_t)n * 128 + qt * 32 + lq) * 4 + 2 * kh + 1];
  f32x16 acc[2];
#pragma unroll
  for (int c = 0; c < 2; ++c) {
    acc[c] = zero16();
    int kt = 2 * kh + c;
#pragma unroll
    for (int ks = 0; ks < 16; ++ks)
      acc[c] = MFMA32(xfrag(kt * 32 + lq, ks), af[ks], acc[c]);
  }
  float mx = -3e38f;
#pragma unroll
  for (int c = 0; c < 2; ++c) {
    unsigned mw = c ? mw1 : mw0;
#pragma unroll
    for (int r = 0; r < 16; ++r) {
      int bit = (r & 3) + 8 * (r >> 2) + 4 * hl;
      float sv = ((mw >> bit) & 1u) ? acc[c][r] * 0.0625f : -6.25e18f;  // -1e20/16
      acc[c][r] = sv;
      mx = fmaxf(mx, sv);
    }
  }
  mx = fmaxf(mx, __shfl_xor(mx, 32));
  float sum = 0.f;
#pragma unroll
  for (int c = 0; c < 2; ++c)
#pragma unroll
    for (int r = 0; r < 16; ++r) {
      float e = __expf(acc[c][r] - mx);
      acc[c][r] = e;
      sum += e;
    }
  sum += __shfl_xor(sum, 32);
  if (lane < 32) {
    float2* s2 = reinterpret_cast<float2*>(scr);
    s2[(qt * 2 + kh) * 32 + lane] = make_float2(mx, sum);
  }
  __syncthreads();                               // b4

  // ---- phase 5: pair-combine; P-frags assembled in-reg -> b128 Pimg writes;
  //               stage Xv; issue Mvo loads
  {
    float2 pr = reinterpret_cast<const float2*>(scr)[(qt * 2 + (kh ^ 1)) * 32 + lq];
    float M = fmaxf(mx, pr.x);
    float tot = sum * __expf(mx - M) + pr.y * __expf(pr.x - M);
    float scale = __expf(mx - M) / tot;
#pragma unroll
    for (int c = 0; c < 2; ++c)
#pragma unroll
      for (int r = 0; r < 16; ++r) acc[c][r] *= scale;
  }
#pragma unroll
  for (int c = 0; c < 2; ++c) {
    int kt = 2 * kh + c;
#pragma unroll
    for (int s16 = 0; s16 < 2; ++s16) {
      float a8[8];
#pragma unroll
      for (int i = 0; i < 8; ++i) a8[i] = acc[c][8 * s16 + i];
      uint4 wd = mkfrag(a8, hl);
      *(uint4*)(Pimg + qt * 8192 + (kt * 2 + s16) * 1024 + lane * 16) = wd;
    }
  }
  flushv(vrp);                                   // Xv -> A
  bf16x8 vf[16];
  {
    const bf16x8* vp = reinterpret_cast<const bf16x8*>(mvo);
#pragma unroll
    for (int ks = 0; ks < 16; ++ks) vf[ks] = vp[(w * 16 + ks) * 64 + lane];
  }
  __syncthreads();                               // b5

  // ---- phase 6: B1 = Xv x Mvo (wave w = e-tile, lane->e, regs->k2),
  //               reshaped in-register to out's A-frags (no LDS image)
  bf16x8 afB1[8];
#pragma unroll
  for (int rt = 0; rt < 4; ++rt) {
    f32x16 a1 = zero16();
#pragma unroll
    for (int ks = 0; ks < 16; ++ks)
      a1 = MFMA32(xfrag(rt * 32 + lq, ks), vf[ks], a1);
#pragma unroll
    for (int s16 = 0; s16 < 2; ++s16) {
      float a8[8];
#pragma unroll
      for (int i = 0; i < 8; ++i) a8[i] = a1[8 * s16 + i];
      afB1[rt * 2 + s16] = u4frag(mkfrag(a8, hl));
    }
  }

  // ---- phase 7: out = B1^T x P + bo (wave w = e-tile, loop qt)
#pragma unroll
  for (int q4 = 0; q4 < 4; ++q4) {
    f32x16 a2 = zero16();
#pragma unroll
    for (int ks = 0; ks < 8; ++ks) {
      bf16x8 pfr = *reinterpret_cast<const bf16x8*>(
          Pimg + q4 * 8192 + ks * 1024 + lane * 16);
      a2 = MFMA32(afB1[ks], pfr, a2);
    }
    float* orow = out + ((size_t)(n * 8192) + (q4 * 32 + lq) * 64 + s) * 256;
#pragma unroll
    for (int a = 0; a < 4; ++a) {
      float4 bv = *reinterpret_cast<const float4*>(bo + w * 32 + 8 * a + 4 * hl);
      float4 st;
      st.x = a2[4*a]   + bv.x; st.y = a2[4*a+1] + bv.y;
      st.z = a2[4*a+2] + bv.z; st.w = a2[4*a+3] + bv.w;
      *reinterpret_cast<float4*>(orow + w * 32 + 8 * a + 4 * hl) = st;
    }
  }
}

extern "C" void kernel_launch(void* const* d_in, const int* in_sizes, int n_in,
                              void* d_out, int out_size, void* d_ws, size_t ws_size,
                              hipStream_t stream) {
  const float* values = (const float*)d_in[0];
  const float* keys   = (const float*)d_in[1];
  const float* query  = (const float*)d_in[2];
  const int*   mask   = (const int*)d_in[3];
  const float* Wq     = (const float*)d_in[4];
  const float* Wk     = (const float*)d_in[5];
  const float* Wv     = (const float*)d_in[6];
  const float* Wo     = (const float*)d_in[7];
  const float* bo     = (const float*)d_in[8];
  float* out = (float*)d_out;

  char* w = (char*)d_ws;
  __bf16*   mqk   = (__bf16*)w;   w += 131072;   // pack [8 ct32][16 ks][64][8]
  __bf16*   mvo   = (__bf16*)w;   w += 131072;
  unsigned* mbits = (unsigned*)w; w += 8192;     // [n][q][4] k-bitwords

  prep_pack<<<dim3(8, 2), 512, 0, stream>>>(Wq, Wk, Wv, Wo, mask, mqk, mvo, mbits);
  fused_attn<<<256, 512, 131072, stream>>>(values, keys, query, mbits,
                                           mqk, mvo, bo, out);
}